// Round 1
// 822.973 us; speedup vs baseline: 1.1009x; 1.1009x over previous
//
#include <hip/hip_runtime.h>

// Problem constants (from reference)
#define NODES  50000
#define EDGES  800000
#define NGRAPH 512

// short-element offsets inside the canonical bf16 weight buffer (wbuf).
// All W matrices are stored TRANSPOSED: Wt[j][k] (128 rows x CH cols), so the
// MFMA B-fragment (8 consecutive k for fixed j) is a contiguous 16B load.
#define OFF_WL0T 0         // [128][64]
#define OFF_WR0T 8192      // [128][64]
#define OFF_WLT  16384     // 11 x [128][128]
#define OFF_WRT  196608    // 11 x [128][128]
#define OFF_B0   376832    // 128
#define OFF_B    376960    // 11*128
#define OFF_HW   378368    // 128*2 (row-major, as input)
#define OFF_HB   378624    // 2
#define WBUF_N   378626

typedef __attribute__((ext_vector_type(8))) short bf16x8;
typedef __attribute__((ext_vector_type(4))) float f32x4;

// ---------- bf16 helpers (internal compute fp32) ----------
__device__ __forceinline__ float bflo(unsigned int u) {
    union { unsigned int i; float f; } c; c.i = u << 16; return c.f;
}
__device__ __forceinline__ float bfhi(unsigned int u) {
    union { unsigned int i; float f; } c; c.i = u & 0xffff0000u; return c.f;
}
__device__ __forceinline__ float bf2f(unsigned short u) {
    union { unsigned int i; float f; } c; c.i = ((unsigned int)u) << 16; return c.f;
}
__device__ __forceinline__ unsigned short f2bf(float f) {
    union { float f; unsigned int i; } c; c.f = f;
    unsigned int u = c.i;
    u = (u + 0x7fffu + ((u >> 16) & 1u)) >> 16;   // round-to-nearest-even
    return (unsigned short)u;
}

// ---------- block-local dtype sniff: bf16 inputs -> 0, fp32 inputs -> 1 ----------
// 64-lane shuffle reduction: MUST be called by ALL lanes of a wave, i.e. before
// any divergent early-return (round-10 bug).
__device__ __forceinline__ int detect_mode(const unsigned int* __restrict__ xu) {
    int bad = 0;
    for (int i = (threadIdx.x & 63); i < 512; i += 64) {
        const unsigned int u = xu[i];
        if (!(fabsf(bflo(u)) < 1e4f)) bad++;   // also catches NaN
        if (!(fabsf(bfhi(u)) < 1e4f)) bad++;
    }
#pragma unroll
    for (int off = 32; off; off >>= 1) bad += __shfl_down(bad, off);
    bad = __shfl(bad, 0);
    return (bad > 16) ? 1 : 0;
}

// ---------- repack weights into canonical bf16 buffer (W's transposed) ----------
__global__ __launch_bounds__(256) void k_cvt_w(const void* xin,
                                               const void* s0, const void* s1, const void* s2,
                                               const void* s3, const void* s4, const void* s5,
                                               const void* s6, const void* s7,
                                               unsigned short* __restrict__ wbuf) {
    const int m = detect_mode((const unsigned int*)xin);   // before any divergent return
    const int i = blockIdx.x * 256 + threadIdx.x;
    if (i >= WBUF_N) return;
    const void* src; int local;
    if (i < OFF_WR0T) {                       // Wl0^T: out(j,k) <- in(k,j), in = 64x128
        const int j = i >> 6, k = i & 63;
        src = s0; local = k * 128 + j;
    } else if (i < OFF_WLT) {                 // Wr0^T
        const int t = i - OFF_WR0T, j = t >> 6, k = t & 63;
        src = s1; local = k * 128 + j;
    } else if (i < OFF_WRT) {                 // Wl^T: 11 x (out(j,k) <- in(k,j)), in = 128x128
        const int t = i - OFF_WLT, l = t >> 14, r = t & 16383, j = r >> 7, k = r & 127;
        src = s3; local = (l << 14) + k * 128 + j;
    } else if (i < OFF_B0) {                  // Wr^T
        const int t = i - OFF_WRT, l = t >> 14, r = t & 16383, j = r >> 7, k = r & 127;
        src = s4; local = (l << 14) + k * 128 + j;
    } else if (i < OFF_B) {
        src = s2; local = i - OFF_B0;         // b0
    } else if (i < OFF_HW) {
        src = s5; local = i - OFF_B;          // b
    } else if (i < OFF_HB) {
        src = s6; local = i - OFF_HW;         // head_W
    } else {
        src = s7; local = i - OFF_HB;         // head_b
    }
    wbuf[i] = m ? f2bf(((const float*)src)[local]) : ((const unsigned short*)src)[local];
}

// ---------- x -> canonical bf16 (N x 64) + zero deg/gsum/gcnt in tail blocks ----------
#define CVT_BLOCKS 1563    // ceil(NODES*64/8 / 256)
#define ZERO_WORDS (NODES + NGRAPH * 128 + NGRAPH)   // deg + gsum + gcnt
__global__ __launch_bounds__(256) void k_cvt_x(const void* __restrict__ xin,
                                               unsigned short* __restrict__ hx,
                                               int* __restrict__ deg,
                                               float* __restrict__ gsum,
                                               float* __restrict__ gcnt) {
    if (blockIdx.x >= CVT_BLOCKS) {           // zeroing tail (block-uniform branch)
        const int i = (blockIdx.x - CVT_BLOCKS) * 256 + threadIdx.x;
        if (i < NODES) deg[i] = 0;
        else if (i < NODES + NGRAPH * 128) gsum[i - NODES] = 0.f;
        else if (i < ZERO_WORDS) gcnt[i - NODES - NGRAPH * 128] = 0.f;
        return;
    }
    const int m = detect_mode((const unsigned int*)xin);   // before divergent return
    const int i = blockIdx.x * 256 + threadIdx.x;   // groups of 8 elements
    if (i >= NODES * 64 / 8) return;
    if (m == 0) {
        ((uint4*)hx)[i] = ((const uint4*)xin)[i];
    } else {
        const float4* f = (const float4*)xin;
        const float4 a = f[2 * i], b = f[2 * i + 1];
        const unsigned int p0 = f2bf(a.x) | ((unsigned int)f2bf(a.y) << 16);
        const unsigned int p1 = f2bf(a.z) | ((unsigned int)f2bf(a.w) << 16);
        const unsigned int p2 = f2bf(b.x) | ((unsigned int)f2bf(b.y) << 16);
        const unsigned int p3 = f2bf(b.z) | ((unsigned int)f2bf(b.w) << 16);
        ((uint4*)hx)[i] = make_uint4(p0, p1, p2, p3);
    }
}

// ---------- CSR build (by dst) ----------
__global__ __launch_bounds__(256) void k_count(const int* __restrict__ ei,
                                               int* __restrict__ deg) {
    const int e = blockIdx.x * 256 + threadIdx.x;
    if (e < EDGES) {
        const int d = ei[EDGES + e];
        if ((unsigned)d < NODES) atomicAdd(&deg[d], 1);
    }
}

__global__ __launch_bounds__(1024) void k_scan_block(const int* __restrict__ deg,
                                                     int* __restrict__ tmp,
                                                     int* __restrict__ bsums) {
    __shared__ int s[1024];
    const int idx = blockIdx.x * 1024 + threadIdx.x;
    s[threadIdx.x] = (idx < NODES) ? deg[idx] : 0;
    __syncthreads();
    for (int off = 1; off < 1024; off <<= 1) {
        int v = (threadIdx.x >= off) ? s[threadIdx.x - off] : 0;
        __syncthreads();
        s[threadIdx.x] += v;
        __syncthreads();
    }
    if (idx < NODES) tmp[idx] = s[threadIdx.x];
    if (threadIdx.x == 1023) bsums[blockIdx.x] = s[1023];
}

__global__ void k_scan_sums(int* __restrict__ bsums, int nb) {
    if (threadIdx.x == 0 && blockIdx.x == 0) {
        int acc = 0;
        for (int i = 0; i < nb; ++i) { int v = bsums[i]; bsums[i] = acc; acc += v; }
    }
}

__global__ __launch_bounds__(1024) void k_scan_fin(const int* __restrict__ deg,
                                                   const int* __restrict__ tmp,
                                                   const int* __restrict__ bsums,
                                                   int* __restrict__ row_ptr,
                                                   int* __restrict__ cursor,
                                                   float* __restrict__ inv_deg) {
    const int idx = blockIdx.x * 1024 + threadIdx.x;
    if (idx >= NODES) return;
    const int incl = tmp[idx] + bsums[blockIdx.x];
    const int d = deg[idx];
    row_ptr[idx + 1] = incl;
    cursor[idx] = incl - d;
    inv_deg[idx] = (d > 0) ? (1.0f / (float)d) : 0.0f;
    if (idx == 0) row_ptr[0] = 0;
}

// plain scatter store (round-11 atomicExch experiment: 46 -> 67 us, WRITE_SIZE
// unchanged -- atomics serialize without reducing writeback amplification).
// csr entries are ushort (src < 50000 < 65536): halves csr READ traffic in
// all 12 conv layers; scatter-write amplification itself is untouched (64B
// line per store either way -- see round-12 counters).
__global__ __launch_bounds__(256) void k_fill(const int* __restrict__ ei,
                                              int* __restrict__ cursor,
                                              unsigned short* __restrict__ csr_src) {
    const int e = blockIdx.x * 256 + threadIdx.x;
    if (e < EDGES) {
        const int d = ei[EDGES + e];
        if ((unsigned)d < NODES) {
            const int p = atomicAdd(&cursor[d], 1);
            csr_src[p] = (unsigned short)ei[e];
        }
    }
}

// ws-too-small sentinel: absmax will read ~(1000 + ws_MB)
__global__ __launch_bounds__(256) void k_ws_stamp(unsigned short* __restrict__ outp, float v) {
    const int t = blockIdx.x * 256 + threadIdx.x;
    if (t < NGRAPH * 2) outp[t] = f2bf(v);
}

// ---------- FUSED SAGE layer: out = act(mean_agg(h) @ Wl + h @ Wr + b) ----------
// Round-12 fusion: the old k_agg wrote a 12.8MB agg buffer that k_gemm
// immediately re-read (25.6MB round trip per layer) and cost a dispatch.
// Now each block aggregates ITS OWN 64 output rows into LDS, barriers once,
// and runs the MFMA loop with A-half-0 fragments read from LDS.
//
// Phase 1 (gather): lane granularity uint4 (16B), LPN = CH/8 lanes per node,
// 8-deep gather batches (same per-channel accumulation order as the old
// uint2 k_agg -> bit-identical numerics). Writes bf16 rows into aggT with
// a +8-short padded stride (byte stride 272/144, 16B-multiple so ds_write/
// read_b128 stay aligned; row step = 4 banks -> reads sit at the b128
// structural floor of 8 bank-cycles, no extra conflicts).
//
// Phase 2 (MFMA): block = 4 waves, tile 64 rows x 128 cols. Wave w: rows
// m0 = blk*64 + (w&1)*32 (2 m-tiles), cols n0 = (w>>1)*64 (4 n-tiles) ->
// 8 MFMAs/step, B-frag reused 2x, register double-buffer on A and B.
// Unified K-loop: steps 0..KC-1 = aggT@Wl (LDS), KC..2KC-1 = h@Wr (global).
// mfma_f32_16x16x32_bf16 layouts (m89/m120-verified):
//   A-frag: lane holds A[m=lane&15][k=quad*8+j]; B-frag: B[k=quad*8+j][n=lane&15]
//   C/D: lane reg r holds D[row=quad*4+r][col=lane&15]
// act: 0=none 1=relu 2=leaky(0.01)
template <int CH>
__global__ __launch_bounds__(256) void k_fused(const unsigned short* __restrict__ h,   // N x CH
                                               const int* __restrict__ row_ptr,
                                               const unsigned short* __restrict__ csr_src,
                                               const float* __restrict__ inv_deg,
                                               const unsigned short* __restrict__ Wt1, // [128][CH]
                                               const unsigned short* __restrict__ Wt2, // [128][CH]
                                               const unsigned short* __restrict__ bias,
                                               unsigned short* __restrict__ outp,      // N x 128
                                               int act) {
    constexpr int LSTR = CH + 8;              // padded LDS stride (shorts)
    constexpr int LPN  = CH / 8;              // uint4 lanes per node (16 or 8)
    constexpr int NPW  = 64 / LPN;            // nodes per wave per iter (4 or 8)
    constexpr int NPB  = NPW * 4;             // nodes per block per iter (16 or 32)
    __shared__ unsigned short aggT[64][LSTR];

    const int wave = threadIdx.x >> 6;
    const int lane = threadIdx.x & 63;

    // ---- phase 1: mean-aggregate this block's 64 rows into LDS ----
    {
        const int sub = lane / LPN;
        const int cl  = lane % LPN;
        const uint4* hb = (const uint4*)h;
#pragma unroll
        for (int it = 0; it < 64 / NPB; ++it) {
            const int rl   = it * NPB + wave * NPW + sub;   // local row 0..63
            const int node = blockIdx.x * 64 + rl;
            float c0 = 0.f, c1 = 0.f, c2 = 0.f, c3 = 0.f;
            float c4 = 0.f, c5 = 0.f, c6 = 0.f, c7 = 0.f;
            if (node < NODES) {
                const int e1 = row_ptr[node + 1];
                int e = row_ptr[node];
                for (; e + 7 < e1; e += 8) {
                    uint4 u[8];
#pragma unroll
                    for (int j = 0; j < 8; ++j)
                        u[j] = hb[(size_t)csr_src[e + j] * LPN + cl];
#pragma unroll
                    for (int j = 0; j < 8; ++j) {
                        c0 += bflo(u[j].x); c1 += bfhi(u[j].x);
                        c2 += bflo(u[j].y); c3 += bfhi(u[j].y);
                        c4 += bflo(u[j].z); c5 += bfhi(u[j].z);
                        c6 += bflo(u[j].w); c7 += bfhi(u[j].w);
                    }
                }
                for (; e < e1; ++e) {
                    const uint4 u = hb[(size_t)csr_src[e] * LPN + cl];
                    c0 += bflo(u.x); c1 += bfhi(u.x);
                    c2 += bflo(u.y); c3 += bfhi(u.y);
                    c4 += bflo(u.z); c5 += bfhi(u.z);
                    c6 += bflo(u.w); c7 += bfhi(u.w);
                }
                const float inv = inv_deg[node];
                c0 *= inv; c1 *= inv; c2 *= inv; c3 *= inv;
                c4 *= inv; c5 *= inv; c6 *= inv; c7 *= inv;
            }
            uint4 o;     // rows >= NODES stay exactly zero (never NaN into MFMA)
            o.x = f2bf(c0) | ((unsigned int)f2bf(c1) << 16);
            o.y = f2bf(c2) | ((unsigned int)f2bf(c3) << 16);
            o.z = f2bf(c4) | ((unsigned int)f2bf(c5) << 16);
            o.w = f2bf(c6) | ((unsigned int)f2bf(c7) << 16);
            *(uint4*)&aggT[rl][cl * 8] = o;
        }
    }
    __syncthreads();

    // ---- phase 2: MFMA ----
    const int quad = lane >> 4;
    const int l16  = lane & 15;
    const int m0l  = (wave & 1) * 32;          // local m-origin of this wave
    const int n0   = (wave >> 1) * 64;
    const int m0   = blockIdx.x * 64 + m0l;
    int rowH0 = m0 + l16;                      // global rows for the h@Wr half
    int rowH1 = m0 + 16 + l16;
    if (rowH0 >= NODES) rowH0 = NODES - 1;     // clamped rows feed MFMA, never stored
    if (rowH1 >= NODES) rowH1 = NODES - 1;

    constexpr int KC = CH / 32;
    constexpr int NS = 2 * KC;

    auto loadA = [&](int s, int rlocal, int growC) -> bf16x8 {
        if (s < KC)
            return *(const bf16x8*)&aggT[rlocal][s * 32 + quad * 8];
        return *(const bf16x8*)(h + (size_t)growC * CH + (s - KC) * 32 + quad * 8);
    };
    auto loadB = [&](int s, int nt) -> bf16x8 {
        const unsigned short* W = (s < KC) ? Wt1 : Wt2;
        const int kc = (s < KC) ? s : s - KC;
        return *(const bf16x8*)(W + (size_t)(n0 + nt * 16 + l16) * CH + kc * 32 + quad * 8);
    };

    f32x4 acc[2][4] = {};
    bf16x8 a0 = loadA(0, m0l + l16, rowH0);
    bf16x8 a1 = loadA(0, m0l + 16 + l16, rowH1);
    bf16x8 b[4];
#pragma unroll
    for (int nt = 0; nt < 4; ++nt) b[nt] = loadB(0, nt);

#pragma unroll
    for (int s = 0; s < NS; ++s) {
        bf16x8 na0, na1, nb[4];
        if (s + 1 < NS) {                      // issue next step's loads first
            na0 = loadA(s + 1, m0l + l16, rowH0);
            na1 = loadA(s + 1, m0l + 16 + l16, rowH1);
#pragma unroll
            for (int nt = 0; nt < 4; ++nt) nb[nt] = loadB(s + 1, nt);
        }
#pragma unroll
        for (int nt = 0; nt < 4; ++nt) {
            acc[0][nt] = __builtin_amdgcn_mfma_f32_16x16x32_bf16(a0, b[nt], acc[0][nt], 0, 0, 0);
            acc[1][nt] = __builtin_amdgcn_mfma_f32_16x16x32_bf16(a1, b[nt], acc[1][nt], 0, 0, 0);
        }
        if (s + 1 < NS) {
            a0 = na0; a1 = na1;
#pragma unroll
            for (int nt = 0; nt < 4; ++nt) b[nt] = nb[nt];
        }
    }

#pragma unroll
    for (int nt = 0; nt < 4; ++nt) {
        const float bj = bf2f(bias[n0 + nt * 16 + l16]);
#pragma unroll
        for (int mt = 0; mt < 2; ++mt) {
#pragma unroll
            for (int r = 0; r < 4; ++r) {
                const int row = m0 + mt * 16 + quad * 4 + r;
                if (row < NODES) {
                    float v = acc[mt][nt][r] + bj;
                    if (act == 1) v = fmaxf(v, 0.f);
                    else if (act == 2) v = v > 0.f ? v : 0.01f * v;
                    outp[(size_t)row * 128 + n0 + nt * 16 + l16] = f2bf(v);
                }
            }
        }
    }
}

// ---------- segmented global mean pool (batch_idx sorted) ----------
// 512 threads = 4 substreams x 128 channels; block covers 128 nodes; substream
// sg scans nodes n0+4i+sg (sorted within stream), flushing at graph transitions.
__global__ __launch_bounds__(512) void k_pool(const unsigned short* __restrict__ h,
                                              const int* __restrict__ batch,
                                              float* __restrict__ gsum,
                                              float* __restrict__ gcnt) {
    const int c = threadIdx.x & 127;
    const int sg = threadIdx.x >> 7;            // 0..3
    const int n0 = blockIdx.x * 128;
    float s = 0.f;
    int cnt = 0, gprev = -1;
#pragma unroll 4
    for (int i = 0; i < 32; ++i) {
        const int n = n0 + i * 4 + sg;
        if (n >= NODES) break;
        int g = batch[n];
        if ((unsigned)g >= NGRAPH) g = (gprev < 0) ? 0 : gprev;
        if (g != gprev) {
            if (gprev >= 0) {
                atomicAdd(&gsum[(size_t)gprev * 128 + c], s);
                if (c == 0) atomicAdd(&gcnt[gprev], (float)cnt);
            }
            s = 0.f; cnt = 0; gprev = g;
        }
        s += bf2f(h[(size_t)n * 128 + c]);
        cnt++;
    }
    if (gprev >= 0) {
        atomicAdd(&gsum[(size_t)gprev * 128 + c], s);
        if (c == 0) atomicAdd(&gcnt[gprev], (float)cnt);
    }
}

// ---------- head: out = pooled @ head_W + head_b (dtype-adaptive store) ----------
__global__ __launch_bounds__(256) void k_head(const float* __restrict__ gsum,
                                              const float* __restrict__ gcnt,
                                              const unsigned short* __restrict__ wbuf,
                                              const void* __restrict__ xin,
                                              void* __restrict__ outp) {
    const int m = detect_mode((const unsigned int*)xin);   // before any divergent return
    const int t = blockIdx.x * 256 + threadIdx.x;
    if (t >= NGRAPH * 2) return;
    const int g = t >> 1, o = t & 1;
    const float inv = 1.0f / fmaxf(gcnt[g], 1.0f);
    float s = bf2f(wbuf[OFF_HB + o]);
    for (int c = 0; c < 128; ++c)
        s += gsum[(size_t)g * 128 + c] * inv * bf2f(wbuf[OFF_HW + c * 2 + o]);
    if (m) ((float*)outp)[t] = s;
    else ((unsigned short*)outp)[t] = f2bf(s);
}

extern "C" void kernel_launch(void* const* d_in, const int* in_sizes, int n_in,
                              void* d_out, int out_size, void* d_ws, size_t ws_size,
                              hipStream_t stream) {
    const void* x     = d_in[0];
    const int*  ei    = (const int*)d_in[1];
    const int*  batch = (const int*)d_in[2];

    // ---- workspace carve-up (~29 MB; ws_size measured 256 MB in round 8) ----
    char* p = (char*)d_ws;
    auto alloc = [&](size_t bytes) -> void* {
        void* r = (void*)p;
        p += (bytes + 255) & ~(size_t)255;
        return r;
    };
    unsigned short* hA   = (unsigned short*)alloc((size_t)NODES * 128 * 2);  // holds x (N x 64) first
    unsigned short* hB   = (unsigned short*)alloc((size_t)NODES * 128 * 2);
    unsigned short* wbuf = (unsigned short*)alloc((size_t)(WBUF_N + 14) * 2);
    int*   deg     = (int*)alloc((size_t)NODES * 4);
    int*   tmp     = (int*)alloc((size_t)NODES * 4);
    int*   row_ptr = (int*)alloc((size_t)(NODES + 1) * 4);
    int*   cursor  = (int*)alloc((size_t)NODES * 4);
    float* inv_deg = (float*)alloc((size_t)NODES * 4);
    unsigned short* csr_src = (unsigned short*)alloc((size_t)EDGES * 2);
    int*   bsums   = (int*)alloc(64 * 4);
    float* gsum    = (float*)alloc((size_t)NGRAPH * 128 * 4);
    float* gcnt    = (float*)alloc((size_t)NGRAPH * 4);
    const size_t need = (size_t)(p - (char*)d_ws);
    (void)in_sizes; (void)n_in; (void)out_size;

    if (ws_size < need) {
        k_ws_stamp<<<4, 256, 0, stream>>>((unsigned short*)d_out,
                                          1000.0f + (float)(ws_size >> 20));
        return;
    }

    // setup: weight repack (mode sniffed block-locally), x convert + zero tail
    const int zeroBlocks = (ZERO_WORDS + 255) / 256;
    k_cvt_w<<<(WBUF_N + 255) / 256, 256, 0, stream>>>(x, d_in[3], d_in[4], d_in[5], d_in[6],
                                                      d_in[7], d_in[8], d_in[9], d_in[10], wbuf);
    k_cvt_x<<<CVT_BLOCKS + zeroBlocks, 256, 0, stream>>>(x, hA, deg, gsum, gcnt);

    // CSR build (by dst)
    const int nbScan = (NODES + 1023) / 1024;   // 49
    k_count<<<(EDGES + 255) / 256, 256, 0, stream>>>(ei, deg);
    k_scan_block<<<nbScan, 1024, 0, stream>>>(deg, tmp, bsums);
    k_scan_sums<<<1, 64, 0, stream>>>(bsums, nbScan);
    k_scan_fin<<<nbScan, 1024, 0, stream>>>(deg, tmp, bsums, row_ptr, cursor, inv_deg);
    k_fill<<<(EDGES + 255) / 256, 256, 0, stream>>>(ei, cursor, csr_src);

    const int gemmGrid = (NODES + 63) / 64;      // 782 (64 rows per block)

    // conv 0: 64 -> 128, ReLU. x in hA (N x 64); fused agg+GEMM -> hB.
    k_fused<64><<<gemmGrid, 256, 0, stream>>>(hA, row_ptr, csr_src, inv_deg,
                                              wbuf + OFF_WL0T, wbuf + OFF_WR0T,
                                              wbuf + OFF_B0, hB, 1);

    // convs 1..11: 128 -> 128, ping-pong hB <-> hA
    unsigned short* cur = hB;
    unsigned short* nxt = hA;
    for (int i = 0; i < 11; ++i) {
        const int ci = i + 1;
        const int act = ((ci + 1) % 4 != 0) ? 1 : ((ci == 3 || ci == 7) ? 2 : 0);
        k_fused<128><<<gemmGrid, 256, 0, stream>>>(cur, row_ptr, csr_src, inv_deg,
                                                   wbuf + OFF_WLT + (size_t)i * 128 * 128,
                                                   wbuf + OFF_WRT + (size_t)i * 128 * 128,
                                                   wbuf + OFF_B + (size_t)i * 128,
                                                   nxt, act);
        unsigned short* t = cur; cur = nxt; nxt = t;
    }

    // pool + head
    k_pool<<<(NODES + 127) / 128, 512, 0, stream>>>(cur, batch, gsum, gcnt);
    k_head<<<(NGRAPH * 2 + 255) / 256, 256, 0, stream>>>(gsum, gcnt, wbuf, x, d_out);
}

// Round 2
// 700.986 us; speedup vs baseline: 1.2924x; 1.1740x over previous
//
#include <hip/hip_runtime.h>

// Problem constants (from reference)
#define NODES  50000
#define EDGES  800000
#define NGRAPH 512

// short-element offsets inside the canonical bf16 weight buffer (wbuf).
// All W matrices are stored TRANSPOSED: Wt[j][k] (128 rows x CH cols), so the
// MFMA B-fragment (8 consecutive k for fixed j) is a contiguous 16B load.
#define OFF_WL0T 0         // [128][64]
#define OFF_WR0T 8192      // [128][64]
#define OFF_WLT  16384     // 11 x [128][128]
#define OFF_WRT  196608    // 11 x [128][128]
#define OFF_B0   376832    // 128
#define OFF_B    376960    // 11*128
#define OFF_HW   378368    // 128*2 (row-major, as input)
#define OFF_HB   378624    // 2
#define WBUF_N   378626

typedef __attribute__((ext_vector_type(8))) short bf16x8;
typedef __attribute__((ext_vector_type(4))) float f32x4;

// ---------- bf16 helpers (internal compute fp32) ----------
__device__ __forceinline__ float bflo(unsigned int u) {
    union { unsigned int i; float f; } c; c.i = u << 16; return c.f;
}
__device__ __forceinline__ float bfhi(unsigned int u) {
    union { unsigned int i; float f; } c; c.i = u & 0xffff0000u; return c.f;
}
__device__ __forceinline__ float bf2f(unsigned short u) {
    union { unsigned int i; float f; } c; c.i = ((unsigned int)u) << 16; return c.f;
}
__device__ __forceinline__ unsigned short f2bf(float f) {
    union { float f; unsigned int i; } c; c.f = f;
    unsigned int u = c.i;
    u = (u + 0x7fffu + ((u >> 16) & 1u)) >> 16;   // round-to-nearest-even
    return (unsigned short)u;
}

// ---------- block-local dtype sniff: bf16 inputs -> 0, fp32 inputs -> 1 ----------
// 64-lane shuffle reduction: MUST be called by ALL lanes of a wave, i.e. before
// any divergent early-return (round-10 bug).
__device__ __forceinline__ int detect_mode(const unsigned int* __restrict__ xu) {
    int bad = 0;
    for (int i = (threadIdx.x & 63); i < 512; i += 64) {
        const unsigned int u = xu[i];
        if (!(fabsf(bflo(u)) < 1e4f)) bad++;   // also catches NaN
        if (!(fabsf(bfhi(u)) < 1e4f)) bad++;
    }
#pragma unroll
    for (int off = 32; off; off >>= 1) bad += __shfl_down(bad, off);
    bad = __shfl(bad, 0);
    return (bad > 16) ? 1 : 0;
}

// ---------- repack weights into canonical bf16 buffer (W's transposed) ----------
__global__ __launch_bounds__(256) void k_cvt_w(const void* xin,
                                               const void* s0, const void* s1, const void* s2,
                                               const void* s3, const void* s4, const void* s5,
                                               const void* s6, const void* s7,
                                               unsigned short* __restrict__ wbuf) {
    const int m = detect_mode((const unsigned int*)xin);   // before any divergent return
    const int i = blockIdx.x * 256 + threadIdx.x;
    if (i >= WBUF_N) return;
    const void* src; int local;
    if (i < OFF_WR0T) {                       // Wl0^T: out(j,k) <- in(k,j), in = 64x128
        const int j = i >> 6, k = i & 63;
        src = s0; local = k * 128 + j;
    } else if (i < OFF_WLT) {                 // Wr0^T
        const int t = i - OFF_WR0T, j = t >> 6, k = t & 63;
        src = s1; local = k * 128 + j;
    } else if (i < OFF_WRT) {                 // Wl^T: 11 x (out(j,k) <- in(k,j)), in = 128x128
        const int t = i - OFF_WLT, l = t >> 14, r = t & 16383, j = r >> 7, k = r & 127;
        src = s3; local = (l << 14) + k * 128 + j;
    } else if (i < OFF_B0) {                  // Wr^T
        const int t = i - OFF_WRT, l = t >> 14, r = t & 16383, j = r >> 7, k = r & 127;
        src = s4; local = (l << 14) + k * 128 + j;
    } else if (i < OFF_B) {
        src = s2; local = i - OFF_B0;         // b0
    } else if (i < OFF_HW) {
        src = s5; local = i - OFF_B;          // b
    } else if (i < OFF_HB) {
        src = s6; local = i - OFF_HW;         // head_W
    } else {
        src = s7; local = i - OFF_HB;         // head_b
    }
    wbuf[i] = m ? f2bf(((const float*)src)[local]) : ((const unsigned short*)src)[local];
}

// ---------- x -> canonical bf16 (N x 64) + zero deg/gsum/gcnt/dummy rows ----------
// Dummy row trick (round 13): CSR is padded per-node to a multiple of 8 with
// index = NODES, which must point at an all-zero feature row so padded gathers
// add exactly 0.0f. hA's 64-wide dummy (conv 0) and both buffers' 128-wide
// dummies (convs 1..11; GEMM never writes row NODES so they stay zero).
#define CVT_BLOCKS 1563    // ceil(NODES*64/8 / 256)
#define ZERO_BASE  (NODES + NGRAPH * 128 + NGRAPH)
#define ZERO_WORDS (ZERO_BASE + 160)   // + hA64 dummy (32w) + hA128 (64w) + hB128 (64w)
__global__ __launch_bounds__(256) void k_cvt_x(const void* __restrict__ xin,
                                               unsigned short* __restrict__ hx,
                                               unsigned short* __restrict__ hB,
                                               int* __restrict__ deg,
                                               float* __restrict__ gsum,
                                               float* __restrict__ gcnt) {
    if (blockIdx.x >= CVT_BLOCKS) {           // zeroing tail (block-uniform branch)
        const int i = (blockIdx.x - CVT_BLOCKS) * 256 + threadIdx.x;
        if (i < NODES) deg[i] = 0;
        else if (i < NODES + NGRAPH * 128) gsum[i - NODES] = 0.f;
        else if (i < ZERO_BASE) gcnt[i - NODES - NGRAPH * 128] = 0.f;
        else if (i < ZERO_BASE + 32)
            ((unsigned int*)(hx + (size_t)NODES * 64))[i - ZERO_BASE] = 0u;
        else if (i < ZERO_BASE + 96)
            ((unsigned int*)(hx + (size_t)NODES * 128))[i - ZERO_BASE - 32] = 0u;
        else if (i < ZERO_WORDS)
            ((unsigned int*)(hB + (size_t)NODES * 128))[i - ZERO_BASE - 96] = 0u;
        return;
    }
    const int m = detect_mode((const unsigned int*)xin);   // before divergent return
    const int i = blockIdx.x * 256 + threadIdx.x;   // groups of 8 elements
    if (i >= NODES * 64 / 8) return;
    if (m == 0) {
        ((uint4*)hx)[i] = ((const uint4*)xin)[i];
    } else {
        const float4* f = (const float4*)xin;
        const float4 a = f[2 * i], b = f[2 * i + 1];
        const unsigned int p0 = f2bf(a.x) | ((unsigned int)f2bf(a.y) << 16);
        const unsigned int p1 = f2bf(a.z) | ((unsigned int)f2bf(a.w) << 16);
        const unsigned int p2 = f2bf(b.x) | ((unsigned int)f2bf(b.y) << 16);
        const unsigned int p3 = f2bf(b.z) | ((unsigned int)f2bf(b.w) << 16);
        ((uint4*)hx)[i] = make_uint4(p0, p1, p2, p3);
    }
}

// ---------- CSR build (by dst), 8-aligned padded rows ----------
__global__ __launch_bounds__(256) void k_count(const int* __restrict__ ei,
                                               int* __restrict__ deg) {
    const int e = blockIdx.x * 256 + threadIdx.x;
    if (e < EDGES) {
        const int d = ei[EDGES + e];
        if ((unsigned)d < NODES) atomicAdd(&deg[d], 1);
    }
}

// scan over PADDED degrees: p = (d+7) & ~7  (8-aligned row starts -> uint4
// index loads in the gather; pad slots point at the zero dummy row)
__global__ __launch_bounds__(1024) void k_scan_block(const int* __restrict__ deg,
                                                     int* __restrict__ tmp,
                                                     int* __restrict__ bsums) {
    __shared__ int s[1024];
    const int idx = blockIdx.x * 1024 + threadIdx.x;
    s[threadIdx.x] = (idx < NODES) ? ((deg[idx] + 7) & ~7) : 0;
    __syncthreads();
    for (int off = 1; off < 1024; off <<= 1) {
        int v = (threadIdx.x >= off) ? s[threadIdx.x - off] : 0;
        __syncthreads();
        s[threadIdx.x] += v;
        __syncthreads();
    }
    if (idx < NODES) tmp[idx] = s[threadIdx.x];
    if (threadIdx.x == 1023) bsums[blockIdx.x] = s[1023];
}

__global__ void k_scan_sums(int* __restrict__ bsums, int nb) {
    if (threadIdx.x == 0 && blockIdx.x == 0) {
        int acc = 0;
        for (int i = 0; i < nb; ++i) { int v = bsums[i]; bsums[i] = acc; acc += v; }
    }
}

__global__ __launch_bounds__(1024) void k_scan_fin(const int* __restrict__ deg,
                                                   const int* __restrict__ tmp,
                                                   const int* __restrict__ bsums,
                                                   int* __restrict__ row_ptr,
                                                   int* __restrict__ cursor,
                                                   float* __restrict__ inv_deg,
                                                   unsigned short* __restrict__ csr_src) {
    const int idx = blockIdx.x * 1024 + threadIdx.x;
    if (idx >= NODES) return;
    const int incl = tmp[idx] + bsums[blockIdx.x];      // padded inclusive scan
    const int d = deg[idx];
    const int p = (d + 7) & ~7;
    const int start = incl - p;
    row_ptr[idx + 1] = incl;
    cursor[idx] = start;
    inv_deg[idx] = (d > 0) ? (1.0f / (float)d) : 0.0f;
    for (int i = d; i < p; ++i) csr_src[start + i] = (unsigned short)NODES;  // pad -> zero row
    if (idx == 0) row_ptr[0] = 0;
}

// plain scatter store (round-11 atomicExch experiment: 46 -> 67 us, WRITE_SIZE
// unchanged -- atomics serialize without reducing writeback amplification).
// csr entries are ushort (src < 50000 < 65536): halves csr READ traffic in
// all 12 conv layers.
__global__ __launch_bounds__(256) void k_fill(const int* __restrict__ ei,
                                              int* __restrict__ cursor,
                                              unsigned short* __restrict__ csr_src) {
    const int e = blockIdx.x * 256 + threadIdx.x;
    if (e < EDGES) {
        const int d = ei[EDGES + e];
        if ((unsigned)d < NODES) {
            const int p = atomicAdd(&cursor[d], 1);
            csr_src[p] = (unsigned short)ei[e];
        }
    }
}

// ws-too-small sentinel: absmax will read ~(1000 + ws_MB)
__global__ __launch_bounds__(256) void k_ws_stamp(unsigned short* __restrict__ outp, float v) {
    const int t = blockIdx.x * 256 + threadIdx.x;
    if (t < NGRAPH * 2) outp[t] = f2bf(v);
}

// ---------- FUSED SAGE layer: out = act(mean_agg(h) @ Wl + h @ Wr + b) ----------
// Round-13 restructure. Round-1 counters (MfmaUtil 2%, VALUBusy 18%, HBM 21%,
// Occ 25.6%) showed the 64-row version latency-bound: grid 782x4 waves = 3128
// of 8192 slots (38% cap), plus an 8-long dependent index-load chain per batch.
//   * 32-row blocks: grid 1563, 6252 waves -> 76% residency cap, finer tail.
//   * padded CSR: row starts 8-aligned, pads point at zero dummy row NODES, so
//     each batch's 8 indices arrive via ONE uint4 load (prefetched one batch
//     ahead) and the divergent per-node tail loop is gone. Adding 0.0f keeps
//     sums bit-identical.
//
// Phase 1 (gather): lane = uint4 (16B), LPN = CH/8 lanes per node, 8-deep
// gather batches (same per-channel accumulation order as before). Rows land in
// LDS aggT with +8-short padded stride.
// Phase 2 (MFMA): 4 waves; wave w owns cols n0 = w*32 over all 32 rows ->
// acc[2][2], 4 MFMAs/step, register double-buffer on A and B. Unified K-loop:
// steps 0..KC-1 = aggT@Wl (LDS), KC..2KC-1 = h@Wr (global).
// mfma_f32_16x16x32_bf16 layouts (m89/m120-verified):
//   A-frag: lane holds A[m=lane&15][k=quad*8+j]; B-frag: B[k=quad*8+j][n=lane&15]
//   C/D: lane reg r holds D[row=quad*4+r][col=lane&15]
// act: 0=none 1=relu 2=leaky(0.01)
template <int CH>
__global__ __launch_bounds__(256) void k_fused(const unsigned short* __restrict__ h,   // N x CH (+ zero row)
                                               const int* __restrict__ row_ptr,
                                               const unsigned short* __restrict__ csr_src,
                                               const float* __restrict__ inv_deg,
                                               const unsigned short* __restrict__ Wt1, // [128][CH]
                                               const unsigned short* __restrict__ Wt2, // [128][CH]
                                               const unsigned short* __restrict__ bias,
                                               unsigned short* __restrict__ outp,      // N x 128
                                               int act) {
    constexpr int LSTR = CH + 8;              // padded LDS stride (shorts)
    constexpr int LPN  = CH / 8;              // uint4 lanes per node (16 or 8)
    constexpr int NPW  = 64 / LPN;            // nodes per wave per iter (4 or 8)
    constexpr int NPB  = NPW * 4;             // nodes per block per iter (16 or 32)
    __shared__ unsigned short aggT[32][LSTR];

    const int wave = threadIdx.x >> 6;
    const int lane = threadIdx.x & 63;

    // ---- phase 1: mean-aggregate this block's 32 rows into LDS ----
    {
        const int sub = lane / LPN;
        const int cl  = lane % LPN;
        const uint4* hb = (const uint4*)h;
#pragma unroll
        for (int it = 0; it < 32 / NPB; ++it) {
            const int rl   = it * NPB + wave * NPW + sub;   // local row 0..31
            const int node = blockIdx.x * 32 + rl;
            float c0 = 0.f, c1 = 0.f, c2 = 0.f, c3 = 0.f;
            float c4 = 0.f, c5 = 0.f, c6 = 0.f, c7 = 0.f;
            if (node < NODES) {
                int e = row_ptr[node];
                const int e1 = row_ptr[node + 1];           // both 8-aligned
                uint4 iv;
                if (e < e1) iv = *(const uint4*)(csr_src + e);
                for (; e < e1; e += 8) {
                    uint4 u[8];
                    u[0] = hb[(size_t)(iv.x & 0xffffu) * LPN + cl];
                    u[1] = hb[(size_t)(iv.x >> 16)     * LPN + cl];
                    u[2] = hb[(size_t)(iv.y & 0xffffu) * LPN + cl];
                    u[3] = hb[(size_t)(iv.y >> 16)     * LPN + cl];
                    u[4] = hb[(size_t)(iv.z & 0xffffu) * LPN + cl];
                    u[5] = hb[(size_t)(iv.z >> 16)     * LPN + cl];
                    u[6] = hb[(size_t)(iv.w & 0xffffu) * LPN + cl];
                    u[7] = hb[(size_t)(iv.w >> 16)     * LPN + cl];
                    if (e + 8 < e1) iv = *(const uint4*)(csr_src + e + 8);  // prefetch
#pragma unroll
                    for (int j = 0; j < 8; ++j) {
                        c0 += bflo(u[j].x); c1 += bfhi(u[j].x);
                        c2 += bflo(u[j].y); c3 += bfhi(u[j].y);
                        c4 += bflo(u[j].z); c5 += bfhi(u[j].z);
                        c6 += bflo(u[j].w); c7 += bfhi(u[j].w);
                    }
                }
                const float inv = inv_deg[node];
                c0 *= inv; c1 *= inv; c2 *= inv; c3 *= inv;
                c4 *= inv; c5 *= inv; c6 *= inv; c7 *= inv;
            }
            uint4 o;     // rows >= NODES stay exactly zero (never NaN into MFMA)
            o.x = f2bf(c0) | ((unsigned int)f2bf(c1) << 16);
            o.y = f2bf(c2) | ((unsigned int)f2bf(c3) << 16);
            o.z = f2bf(c4) | ((unsigned int)f2bf(c5) << 16);
            o.w = f2bf(c6) | ((unsigned int)f2bf(c7) << 16);
            *(uint4*)&aggT[rl][cl * 8] = o;
        }
    }
    __syncthreads();

    // ---- phase 2: MFMA ----
    const int quad = lane >> 4;
    const int l16  = lane & 15;
    const int n0   = wave * 32;                // this wave's column origin
    const int m0   = blockIdx.x * 32;
    int rowH0 = m0 + l16;                      // global rows for the h@Wr half
    int rowH1 = m0 + 16 + l16;
    if (rowH0 >= NODES) rowH0 = NODES - 1;     // clamped rows feed MFMA, never stored
    if (rowH1 >= NODES) rowH1 = NODES - 1;

    constexpr int KC = CH / 32;
    constexpr int NS = 2 * KC;

    auto loadA = [&](int s, int rlocal, int growC) -> bf16x8 {
        if (s < KC)
            return *(const bf16x8*)&aggT[rlocal][s * 32 + quad * 8];
        return *(const bf16x8*)(h + (size_t)growC * CH + (s - KC) * 32 + quad * 8);
    };
    auto loadB = [&](int s, int nt) -> bf16x8 {
        const unsigned short* W = (s < KC) ? Wt1 : Wt2;
        const int kc = (s < KC) ? s : s - KC;
        return *(const bf16x8*)(W + (size_t)(n0 + nt * 16 + l16) * CH + kc * 32 + quad * 8);
    };

    f32x4 acc[2][2] = {};
    bf16x8 a0 = loadA(0, l16, rowH0);
    bf16x8 a1 = loadA(0, 16 + l16, rowH1);
    bf16x8 b[2];
#pragma unroll
    for (int nt = 0; nt < 2; ++nt) b[nt] = loadB(0, nt);

#pragma unroll
    for (int s = 0; s < NS; ++s) {
        bf16x8 na0, na1, nb[2];
        if (s + 1 < NS) {                      // issue next step's loads first
            na0 = loadA(s + 1, l16, rowH0);
            na1 = loadA(s + 1, 16 + l16, rowH1);
#pragma unroll
            for (int nt = 0; nt < 2; ++nt) nb[nt] = loadB(s + 1, nt);
        }
#pragma unroll
        for (int nt = 0; nt < 2; ++nt) {
            acc[0][nt] = __builtin_amdgcn_mfma_f32_16x16x32_bf16(a0, b[nt], acc[0][nt], 0, 0, 0);
            acc[1][nt] = __builtin_amdgcn_mfma_f32_16x16x32_bf16(a1, b[nt], acc[1][nt], 0, 0, 0);
        }
        if (s + 1 < NS) {
            a0 = na0; a1 = na1;
#pragma unroll
            for (int nt = 0; nt < 2; ++nt) b[nt] = nb[nt];
        }
    }

#pragma unroll
    for (int nt = 0; nt < 2; ++nt) {
        const float bj = bf2f(bias[n0 + nt * 16 + l16]);
#pragma unroll
        for (int mt = 0; mt < 2; ++mt) {
#pragma unroll
            for (int r = 0; r < 4; ++r) {
                const int row = m0 + mt * 16 + quad * 4 + r;
                if (row < NODES) {
                    float v = acc[mt][nt][r] + bj;
                    if (act == 1) v = fmaxf(v, 0.f);
                    else if (act == 2) v = v > 0.f ? v : 0.01f * v;
                    outp[(size_t)row * 128 + n0 + nt * 16 + l16] = f2bf(v);
                }
            }
        }
    }
}

// ---------- segmented global mean pool (batch_idx sorted) ----------
// 512 threads = 4 substreams x 128 channels; block covers 128 nodes; substream
// sg scans nodes n0+4i+sg (sorted within stream), flushing at graph transitions.
__global__ __launch_bounds__(512) void k_pool(const unsigned short* __restrict__ h,
                                              const int* __restrict__ batch,
                                              float* __restrict__ gsum,
                                              float* __restrict__ gcnt) {
    const int c = threadIdx.x & 127;
    const int sg = threadIdx.x >> 7;            // 0..3
    const int n0 = blockIdx.x * 128;
    float s = 0.f;
    int cnt = 0, gprev = -1;
#pragma unroll 4
    for (int i = 0; i < 32; ++i) {
        const int n = n0 + i * 4 + sg;
        if (n >= NODES) break;
        int g = batch[n];
        if ((unsigned)g >= NGRAPH) g = (gprev < 0) ? 0 : gprev;
        if (g != gprev) {
            if (gprev >= 0) {
                atomicAdd(&gsum[(size_t)gprev * 128 + c], s);
                if (c == 0) atomicAdd(&gcnt[gprev], (float)cnt);
            }
            s = 0.f; cnt = 0; gprev = g;
        }
        s += bf2f(h[(size_t)n * 128 + c]);
        cnt++;
    }
    if (gprev >= 0) {
        atomicAdd(&gsum[(size_t)gprev * 128 + c], s);
        if (c == 0) atomicAdd(&gcnt[gprev], (float)cnt);
    }
}

// ---------- head: out = pooled @ head_W + head_b (dtype-adaptive store) ----------
__global__ __launch_bounds__(256) void k_head(const float* __restrict__ gsum,
                                              const float* __restrict__ gcnt,
                                              const unsigned short* __restrict__ wbuf,
                                              const void* __restrict__ xin,
                                              void* __restrict__ outp) {
    const int m = detect_mode((const unsigned int*)xin);   // before any divergent return
    const int t = blockIdx.x * 256 + threadIdx.x;
    if (t >= NGRAPH * 2) return;
    const int g = t >> 1, o = t & 1;
    const float inv = 1.0f / fmaxf(gcnt[g], 1.0f);
    float s = bf2f(wbuf[OFF_HB + o]);
    for (int c = 0; c < 128; ++c)
        s += gsum[(size_t)g * 128 + c] * inv * bf2f(wbuf[OFF_HW + c * 2 + o]);
    if (m) ((float*)outp)[t] = s;
    else ((unsigned short*)outp)[t] = f2bf(s);
}

extern "C" void kernel_launch(void* const* d_in, const int* in_sizes, int n_in,
                              void* d_out, int out_size, void* d_ws, size_t ws_size,
                              hipStream_t stream) {
    const void* x     = d_in[0];
    const int*  ei    = (const int*)d_in[1];
    const int*  batch = (const int*)d_in[2];

    // ---- workspace carve-up (~29 MB; ws_size measured 256 MB in round 8) ----
    char* p = (char*)d_ws;
    auto alloc = [&](size_t bytes) -> void* {
        void* r = (void*)p;
        p += (bytes + 255) & ~(size_t)255;
        return r;
    };
    // +128 shorts: zero dummy row (index NODES) for padded-CSR gathers
    unsigned short* hA   = (unsigned short*)alloc(((size_t)NODES * 128 + 128) * 2);
    unsigned short* hB   = (unsigned short*)alloc(((size_t)NODES * 128 + 128) * 2);
    unsigned short* wbuf = (unsigned short*)alloc((size_t)(WBUF_N + 14) * 2);
    int*   deg     = (int*)alloc((size_t)NODES * 4);
    int*   tmp     = (int*)alloc((size_t)NODES * 4);
    int*   row_ptr = (int*)alloc((size_t)(NODES + 1) * 4);
    int*   cursor  = (int*)alloc((size_t)NODES * 4);
    float* inv_deg = (float*)alloc((size_t)NODES * 4);
    unsigned short* csr_src = (unsigned short*)alloc((size_t)(EDGES + 8 * NODES) * 2); // padded
    int*   bsums   = (int*)alloc(64 * 4);
    float* gsum    = (float*)alloc((size_t)NGRAPH * 128 * 4);
    float* gcnt    = (float*)alloc((size_t)NGRAPH * 4);
    const size_t need = (size_t)(p - (char*)d_ws);
    (void)in_sizes; (void)n_in; (void)out_size;

    if (ws_size < need) {
        k_ws_stamp<<<4, 256, 0, stream>>>((unsigned short*)d_out,
                                          1000.0f + (float)(ws_size >> 20));
        return;
    }

    // setup: weight repack (mode sniffed block-locally), x convert + zero tail
    const int zeroBlocks = (ZERO_WORDS + 255) / 256;
    k_cvt_w<<<(WBUF_N + 255) / 256, 256, 0, stream>>>(x, d_in[3], d_in[4], d_in[5], d_in[6],
                                                      d_in[7], d_in[8], d_in[9], d_in[10], wbuf);
    k_cvt_x<<<CVT_BLOCKS + zeroBlocks, 256, 0, stream>>>(x, hA, hB, deg, gsum, gcnt);

    // CSR build (by dst), 8-aligned padded rows
    const int nbScan = (NODES + 1023) / 1024;   // 49
    k_count<<<(EDGES + 255) / 256, 256, 0, stream>>>(ei, deg);
    k_scan_block<<<nbScan, 1024, 0, stream>>>(deg, tmp, bsums);
    k_scan_sums<<<1, 64, 0, stream>>>(bsums, nbScan);
    k_scan_fin<<<nbScan, 1024, 0, stream>>>(deg, tmp, bsums, row_ptr, cursor, inv_deg, csr_src);
    k_fill<<<(EDGES + 255) / 256, 256, 0, stream>>>(ei, cursor, csr_src);

    const int gemmGrid = (NODES + 31) / 32;      // 1563 (32 rows per block)

    // conv 0: 64 -> 128, ReLU. x in hA (N x 64); fused agg+GEMM -> hB.
    k_fused<64><<<gemmGrid, 256, 0, stream>>>(hA, row_ptr, csr_src, inv_deg,
                                              wbuf + OFF_WL0T, wbuf + OFF_WR0T,
                                              wbuf + OFF_B0, hB, 1);

    // convs 1..11: 128 -> 128, ping-pong hB <-> hA
    unsigned short* cur = hB;
    unsigned short* nxt = hA;
    for (int i = 0; i < 11; ++i) {
        const int ci = i + 1;
        const int act = ((ci + 1) % 4 != 0) ? 1 : ((ci == 3 || ci == 7) ? 2 : 0);
        k_fused<128><<<gemmGrid, 256, 0, stream>>>(cur, row_ptr, csr_src, inv_deg,
                                                   wbuf + OFF_WLT + (size_t)i * 128 * 128,
                                                   wbuf + OFF_WRT + (size_t)i * 128 * 128,
                                                   wbuf + OFF_B + (size_t)i * 128,
                                                   nxt, act);
        unsigned short* t = cur; cur = nxt; nxt = t;
    }

    // pool + head
    k_pool<<<(NODES + 127) / 128, 512, 0, stream>>>(cur, batch, gsum, gcnt);
    k_head<<<(NGRAPH * 2 + 255) / 256, 256, 0, stream>>>(gsum, gcnt, wbuf, x, d_out);
}